// Round 13
// baseline (10806.765 us; speedup 1.0000x reference)
//
#include <hip/hip_runtime.h>

// 2-layer GRU scan: L=512, B=256, D=H=512, 3H=1536.
// Persistent cooperative kernel: 256 blocks (1/CU, LDS-pinned) x 512 threads.
// 8 groups x 32 blocks (g=bid&7); group owns 32 batch rows; layer0 step s and
// layer1 step s-1 run concurrently; ONE group barrier per super-step.
//
// R13 = R12 + gi1 folded into role0 (burst reduction):
//  role0 and role2 both loaded the SAME h0[s-1] tile (gh0=h0@Wh0, gi1=h0@Wi1).
//  role0 now computes BOTH (96 MFMAs, one fabric tile) and hands gi1 to role2
//  via a 3KB fp16 LDS buffer. role2 = epilogue only (no fabric load, no MFMA).
//  Fabric h-burst: 24.6 -> 16.4 MB/step (-33%); one load-RT off role2's path.
//  Barrier (R9/R12-proven): atomic flag store own slot + 32-slot parallel
//  atomic poll + ballot, sleep(8); h-state sc0 sc1 at IF$ (lockstep -> IF$ hits).

#define LSEQ 512
#define TH3 1536

// ws layout (bytes)
#define WT_OFF   0                         // half WT[4][32][16][3][64][8] = 6291456
#define H0_OFF   6291456                   // half h0buf[8][2][32][512]    = 524288
#define H1_OFF   6815744                   // half h1buf[8][2][32][512]    = 524288
#define FBAR_OFF 7340032                   // flag[8][32][128B]            = 32768

typedef _Float16 f16x8 __attribute__((ext_vector_type(8)));
typedef float f32x4 __attribute__((ext_vector_type(4)));

__device__ __forceinline__ float sig_(float v) { return 1.0f / (1.0f + __expf(-v)); }
__device__ __forceinline__ float tanh_(float v) { return 2.0f / (1.0f + __expf(-2.0f * v)) - 1.0f; }

// h-state transport: IF$ coherence point (R2/R6/R9-proven).
__device__ __forceinline__ f32x4 load16b(const void* p) {
  f32x4 r;
  asm volatile("global_load_dwordx4 %0, %1, off sc0 sc1" : "=v"(r) : "v"(p));
  return r;  // NOT ready until s_waitcnt vmcnt(0)
}
__device__ __forceinline__ void store2b(_Float16* p, _Float16 v) {
  asm volatile("global_store_short %0, %1, off sc0 sc1" :: "v"(p), "v"(v) : "memory");
}
__device__ __forceinline__ void astore(unsigned int* p, unsigned int v) {
  __hip_atomic_store(p, v, __ATOMIC_RELAXED, __HIP_MEMORY_SCOPE_AGENT);
}
__device__ __forceinline__ unsigned int aload(unsigned int* p) {
  return __hip_atomic_load(p, __ATOMIC_RELAXED, __HIP_MEMORY_SCOPE_AGENT);
}

// Prologue flag barrier (R9 structure, throttled poll).
__device__ __forceinline__ void gbarrier(char* fb, unsigned int* myflag, int tid, int lane,
                                         unsigned int k) {
  __syncthreads();
  if (tid < 64) {
    const unsigned int tgt = k + 1;
    if (tid == 0) astore(myflag, tgt);
    unsigned int* p = (unsigned int*)(fb + (lane & 31) * 128);
    while (__ballot(aload(p) >= tgt) != ~0ull) __builtin_amdgcn_s_sleep(8);
  }
  __syncthreads();
}

// Weight transpose fp32 -> fp16 MFMA B-fragment layout (unchanged).
__global__ void prep_kernel(const float* __restrict__ Wh0, const float* __restrict__ Wi1,
                            const float* __restrict__ Wh1, const float* __restrict__ Wi0,
                            char* __restrict__ ws) {
  const int b = blockIdx.x;          // 2048 blocks
  const int w = b >> 9;              // 0:Wh0 1:Wi1 2:Wh1 3:Wi0
  const int k = b & 511;
  const float* src = (w == 0) ? Wh0 : (w == 1) ? Wi1 : (w == 2) ? Wh1 : Wi0;
  _Float16* dst = (_Float16*)(ws + WT_OFF);
  const int kc = k >> 5;
  const int lthi = ((k >> 3) & 3) << 4;
  const int e = k & 7;
  for (int col = threadIdx.x; col < TH3; col += 256) {
    float v = src[(size_t)k * TH3 + col];
    int nt = col >> 9, c = col & 511, cid = c >> 4, j = c & 15;
    size_t idx = (size_t)(w * 32 + cid) * 24576 + (size_t)((kc * 3 + nt) * 64 + lthi + j) * 8 + e;
    dst[idx] = (_Float16)v;
  }
  if (b == 0) {  // zero barrier flags (every call, stream-ordered)
    unsigned int* z = (unsigned int*)(ws + FBAR_OFF);
    for (int i = threadIdx.x; i < 8192; i += 256) z[i] = 0u;
  }
}

__global__ void __launch_bounds__(512, 2)
gru_kernel(const float* __restrict__ carry, const float* __restrict__ x,
           const float* __restrict__ bh0, const float* __restrict__ bh1,
           float* __restrict__ out, char* __restrict__ ws) {
  extern __shared__ char smem[];
  _Float16* Wlds = (_Float16*)smem;          // 147456 B: Wh0,Wi1,Wh1 fragment slices
  float* GH0f = (float*)(smem + 147456);     // 6144 B: gh0 [3 nt][32 row][16 col] f32
  float* GH1f = (float*)(smem + 153600);     // 6144 B: gh1 [3 nt][32 row][16 col] f32
  _Float16* GI1h = (_Float16*)(smem + 159744);  // 3072 B: gi1 [3 nt][32 row][16 col] fp16
  // total dynamic LDS = 162816 B (<= 163840)

  const int tid = threadIdx.x;
  const int wid = tid >> 6, lane = tid & 63;
  const int l16 = lane & 15, lhi = lane >> 4;
  const int mhalf = wid & 1, role = wid >> 1;  // 0:gh0+gi1 1:gi0+ep0 2:ep1 3:gh1
  const int g = blockIdx.x & 7, cid = blockIdx.x >> 3;

  _Float16* wt = (_Float16*)(ws + WT_OFF);
  _Float16* h0buf = (_Float16*)(ws + H0_OFF) + (size_t)g * 32768;  // [2 parity][32 row][512]
  _Float16* h1buf = (_Float16*)(ws + H1_OFF) + (size_t)g * 32768;
  char* fb = ws + FBAR_OFF + (size_t)g * 32 * 128;
  unsigned int* myflag = (unsigned int*)(fb + cid * 128);
  unsigned int k = 0;

  // Stage this CU's recurrent-weight fragments into LDS.
  for (int w = 0; w < 3; ++w) {
    const f16x8* s8 = (const f16x8*)(wt + (size_t)(w * 32 + cid) * 24576);
    f16x8* d8 = (f16x8*)(Wlds + w * 24576);
    for (int i = tid; i < 3072; i += 512) d8[i] = s8[i];
  }

  const int hcol = cid * 16 + l16;
  const int rowq0 = mhalf * 16 + 4 * lhi;  // acc-tile rows rowq0+q (m89-verified C/D layout)

  float bR = 0.f, bZ = 0.f, bN = 0.f;
  f32x4 hst = {0.f, 0.f, 0.f, 0.f};  // fp32 recurrent state (roles 1,2)
  if (role == 1 || role == 2) {
    const float* bh = (role == 1) ? bh0 : bh1;
    bR = bh[hcol]; bZ = bh[512 + hcol]; bN = bh[1024 + hcol];
    const int loff = (role == 1) ? 0 : 512;
    _Float16* hb = (role == 1) ? h0buf : h1buf;
#pragma unroll
    for (int q = 0; q < 4; ++q) {
      float h = carry[(size_t)(g * 32 + rowq0 + q) * 1024 + loff + hcol];
      hst[q] = h;
      store2b(&hb[16384 + (rowq0 + q) * 512 + hcol], (_Float16)h);  // prefill parity-1
    }
    asm volatile("s_waitcnt vmcnt(0)" ::: "memory");
  }
  gbarrier(fb, myflag, tid, lane, ++k);

  const f16x8* Wb0 = (const f16x8*)Wlds;                 // Wh0 frags (LDS)
  const f16x8* Wb1 = (const f16x8*)(Wlds + 24576);       // Wi1 frags (LDS)
  const f16x8* Wb2 = (const f16x8*)(Wlds + 2 * 24576);   // Wh1 frags (LDS)
  const f16x8* WbX = (const f16x8*)(wt + (size_t)(3 * 32 + cid) * 24576);  // Wi0 frags (L2)

  for (int s = 0; s <= LSEQ; ++s) {
    const int pr = (s + 1) & 1;  // parity of state[s-1]
    const int pw = s & 1;        // parity of state[s] / state[s-2]
    f32x4 a0 = {0,0,0,0}, a1 = {0,0,0,0}, a2 = {0,0,0,0};

    if (role == 0) {  // gh0 = h0[s-1]@Wh0 AND gi1 = h0[s-1]@Wi1 (one fabric tile, 96 MFMA)
      const _Float16* Ap = h0buf + pr * 16384 + (mhalf * 16 + l16) * 512 + 8 * lhi;
      f16x8 afr[16];
#pragma unroll
      for (int kc = 0; kc < 16; ++kc) afr[kc] = __builtin_bit_cast(f16x8, load16b(Ap + kc * 32));
      asm volatile("s_waitcnt vmcnt(0)" ::: "memory");
      __builtin_amdgcn_sched_barrier(0);
      f32x4 b0 = {0,0,0,0}, b1 = {0,0,0,0}, b2 = {0,0,0,0};
#pragma unroll
      for (int kc = 0; kc < 16; ++kc) {
        a0 = __builtin_amdgcn_mfma_f32_16x16x32_f16(afr[kc], Wb0[(kc*3+0)*64+lane], a0, 0,0,0);
        a1 = __builtin_amdgcn_mfma_f32_16x16x32_f16(afr[kc], Wb0[(kc*3+1)*64+lane], a1, 0,0,0);
        a2 = __builtin_amdgcn_mfma_f32_16x16x32_f16(afr[kc], Wb0[(kc*3+2)*64+lane], a2, 0,0,0);
        b0 = __builtin_amdgcn_mfma_f32_16x16x32_f16(afr[kc], Wb1[(kc*3+0)*64+lane], b0, 0,0,0);
        b1 = __builtin_amdgcn_mfma_f32_16x16x32_f16(afr[kc], Wb1[(kc*3+1)*64+lane], b1, 0,0,0);
        b2 = __builtin_amdgcn_mfma_f32_16x16x32_f16(afr[kc], Wb1[(kc*3+2)*64+lane], b2, 0,0,0);
      }
#pragma unroll
      for (int q = 0; q < 4; ++q) {
        const int row = rowq0 + q;
        GH0f[(0*32 + row)*16 + l16] = a0[q];
        GH0f[(1*32 + row)*16 + l16] = a1[q];
        GH0f[(2*32 + row)*16 + l16] = a2[q];
        GI1h[(0*32 + row)*16 + l16] = (_Float16)b0[q];
        GI1h[(1*32 + row)*16 + l16] = (_Float16)b1[q];
        GI1h[(2*32 + row)*16 + l16] = (_Float16)b2[q];
      }
    } else if (role == 3 && s >= 1) {       // gh1 = h1[s-2] @ Wh1
      const _Float16* Ap = h1buf + pw * 16384 + (mhalf * 16 + l16) * 512 + 8 * lhi;
      f16x8 afr[16];
#pragma unroll
      for (int kc = 0; kc < 16; ++kc) afr[kc] = __builtin_bit_cast(f16x8, load16b(Ap + kc * 32));
      asm volatile("s_waitcnt vmcnt(0)" ::: "memory");
      __builtin_amdgcn_sched_barrier(0);
#pragma unroll
      for (int kc = 0; kc < 16; ++kc) {
        a0 = __builtin_amdgcn_mfma_f32_16x16x32_f16(afr[kc], Wb2[(kc*3+0)*64+lane], a0, 0,0,0);
        a1 = __builtin_amdgcn_mfma_f32_16x16x32_f16(afr[kc], Wb2[(kc*3+1)*64+lane], a1, 0,0,0);
        a2 = __builtin_amdgcn_mfma_f32_16x16x32_f16(afr[kc], Wb2[(kc*3+2)*64+lane], a2, 0,0,0);
      }
#pragma unroll
      for (int q = 0; q < 4; ++q) {
        const int row = rowq0 + q;
        GH1f[(0*32 + row)*16 + l16] = a0[q];
        GH1f[(1*32 + row)*16 + l16] = a1[q];
        GH1f[(2*32 + row)*16 + l16] = a2[q];
      }
    } else if (role == 1 && s < LSEQ) {     // gi0 = x[s] @ Wi0
      const float* xp = x + ((size_t)s * 256 + g * 32 + mhalf * 16 + l16) * 512 + 8 * lhi;
#pragma unroll
      for (int kc = 0; kc < 16; ++kc) {
        f32x4 xa = *(const f32x4*)(xp + kc * 32);
        f32x4 xb = *(const f32x4*)(xp + kc * 32 + 4);
        f16x8 a;
        a[0]=(_Float16)xa[0]; a[1]=(_Float16)xa[1]; a[2]=(_Float16)xa[2]; a[3]=(_Float16)xa[3];
        a[4]=(_Float16)xb[0]; a[5]=(_Float16)xb[1]; a[6]=(_Float16)xb[2]; a[7]=(_Float16)xb[3];
        a0 = __builtin_amdgcn_mfma_f32_16x16x32_f16(a, WbX[(kc*3+0)*64+lane], a0, 0,0,0);
        a1 = __builtin_amdgcn_mfma_f32_16x16x32_f16(a, WbX[(kc*3+1)*64+lane], a1, 0,0,0);
        a2 = __builtin_amdgcn_mfma_f32_16x16x32_f16(a, WbX[(kc*3+2)*64+lane], a2, 0,0,0);
      }
    }
    __syncthreads();  // GH0/GH1/GI1 visible in LDS

    if (role == 1 && s < LSEQ) {            // layer-0 epilogue -> h0[s]
#pragma unroll
      for (int q = 0; q < 4; ++q) {
        const int row = rowq0 + q;
        float r = sig_(a0[q] + GH0f[(0*32 + row)*16 + l16] + bR);
        float z = sig_(a1[q] + GH0f[(1*32 + row)*16 + l16] + bZ);
        float n = tanh_(a2[q] + r * (GH0f[(2*32 + row)*16 + l16] + bN));
        float h = (1.0f - z) * n + z * hst[q];
        hst[q] = h;
        store2b(&h0buf[pw * 16384 + row * 512 + hcol], (_Float16)h);
        if (s == LSEQ - 1) out[(size_t)(g * 32 + row) * 1024 + hcol] = h;  // carry h0
      }
      asm volatile("s_waitcnt vmcnt(0)" ::: "memory");
    } else if (role == 2 && s >= 1) {       // layer-1 epilogue -> h1[s-1] (gi1 from LDS)
#pragma unroll
      for (int q = 0; q < 4; ++q) {
        const int row = rowq0 + q;
        float giR = (float)GI1h[(0*32 + row)*16 + l16];
        float giZ = (float)GI1h[(1*32 + row)*16 + l16];
        float giN = (float)GI1h[(2*32 + row)*16 + l16];
        float r = sig_(giR + GH1f[(0*32 + row)*16 + l16] + bR);
        float z = sig_(giZ + GH1f[(1*32 + row)*16 + l16] + bZ);
        float n = tanh_(giN + r * (GH1f[(2*32 + row)*16 + l16] + bN));
        float h = (1.0f - z) * n + z * hst[q];
        hst[q] = h;
        store2b(&h1buf[pr * 16384 + row * 512 + hcol], (_Float16)h);
        if (s == LSEQ) out[(size_t)(g * 32 + row) * 1024 + 512 + hcol] = h;  // carry h1
      }
      asm volatile("s_waitcnt vmcnt(0)" ::: "memory");
      // y[s-1] issued in the barrier's shadow below (R12).
    }

    // ---- inlined step barrier: post flag, issue y in its shadow, poll ----
    ++k;
    __syncthreads();  // all waves' VMEM drained (vmcnt(0) before s_barrier)
    {
      const unsigned int tgt = k + 1;
      if (tid == 0) astore(myflag, tgt);
      if (role == 2 && s >= 1) {  // y[s-1] = hst (plain cached stores; drain hidden under poll)
#pragma unroll
        for (int q = 0; q < 4; ++q)
          out[(size_t)262144 + ((size_t)(s - 1) * 256 + g * 32 + rowq0 + q) * 512 + hcol] = hst[q];
      }
      if (tid < 64) {
        unsigned int* p = (unsigned int*)(fb + (lane & 31) * 128);
        while (__ballot(aload(p) >= tgt) != ~0ull) __builtin_amdgcn_s_sleep(8);
      }
    }
    __syncthreads();
  }
}

extern "C" void kernel_launch(void* const* d_in, const int* in_sizes, int n_in,
                              void* d_out, int out_size, void* d_ws, size_t ws_size,
                              hipStream_t stream) {
  const float* carry = (const float*)d_in[0];
  const float* x     = (const float*)d_in[1];
  const float* Wi0   = (const float*)d_in[2];
  const float* Wh0   = (const float*)d_in[3];
  const float* bh0   = (const float*)d_in[4];
  const float* Wi1   = (const float*)d_in[5];
  const float* Wh1   = (const float*)d_in[6];
  const float* bh1   = (const float*)d_in[7];
  float* out = (float*)d_out;
  char* ws = (char*)d_ws;

  prep_kernel<<<2048, 256, 0, stream>>>(Wh0, Wi1, Wh1, Wi0, ws);

  (void)hipFuncSetAttribute(reinterpret_cast<const void*>(gru_kernel),
                            hipFuncAttributeMaxDynamicSharedMemorySize, 162816);

  void* args[] = {(void*)&carry, (void*)&x, (void*)&bh0, (void*)&bh1, (void*)&out, (void*)&ws};
  (void)hipLaunchCooperativeKernel(reinterpret_cast<void*>(gru_kernel),
                                   dim3(256), dim3(512), args, 162816, stream);
}